// Round 1
// baseline (77.141 us; speedup 1.0000x reference)
//
#include <hip/hip_runtime.h>

// PairwiseRankingLoss: B=64, N=1024, margin=1.0
//   valid = ~isnan(targets); pairs (i,j), i!=j, both valid
//   loss_ij = relu(1 - (p_i - p_j)) if t_i > t_j else relu(1 + (p_i - p_j))
//   sample_loss = sum_ij / max(n_valid*(n_valid-1), 1)
//   out = mean over samples with n_valid > 1 (0 if none)

#define BN 1024   // items per sample
#define NB 64     // samples

// ---------------- Kernel A: pairwise partial sums ----------------
// grid = NB * 16 blocks: part = (row-quarter<<2) | j-quarter
// block = 256 threads; thread owns row i = prow*256+tid, loops j-quarter in LDS
__global__ __launch_bounds__(256) void prl_pairs(const float* __restrict__ P,
                                                 const float* __restrict__ T,
                                                 float* __restrict__ ws_loss) {
    const int b    = blockIdx.x >> 4;
    const int part = blockIdx.x & 15;
    const int prow = part >> 2;
    const int pj   = part & 3;
    const int tid  = threadIdx.x;

    __shared__ __align__(16) float sp[256];
    __shared__ __align__(16) float st[256];

    const int jbase = pj * 256;
    sp[tid] = P[b * BN + jbase + tid];
    st[tid] = T[b * BN + jbase + tid];
    __syncthreads();

    const int i = prow * 256 + tid;
    const float pi = P[b * BN + i];
    const float ti = T[b * BN + i];
    const bool vi = (ti == ti);   // row valid (not NaN)

    float acc = 0.0f;
    if (vi) {
        const float4* sp4 = (const float4*)sp;
        const float4* st4 = (const float4*)st;
        #pragma unroll 8
        for (int jj = 0; jj < 64; ++jj) {
            const float4 p4 = sp4[jj];   // broadcast LDS reads (all lanes same addr)
            const float4 t4 = st4[jj];
            {
                float d = pi - p4.x;
                float l = (ti > t4.x) ? fmaxf(1.0f - d, 0.0f) : fmaxf(1.0f + d, 0.0f);
                acc += (t4.x == t4.x) ? l : 0.0f;
            }
            {
                float d = pi - p4.y;
                float l = (ti > t4.y) ? fmaxf(1.0f - d, 0.0f) : fmaxf(1.0f + d, 0.0f);
                acc += (t4.y == t4.y) ? l : 0.0f;
            }
            {
                float d = pi - p4.z;
                float l = (ti > t4.z) ? fmaxf(1.0f - d, 0.0f) : fmaxf(1.0f + d, 0.0f);
                acc += (t4.z == t4.z) ? l : 0.0f;
            }
            {
                float d = pi - p4.w;
                float l = (ti > t4.w) ? fmaxf(1.0f - d, 0.0f) : fmaxf(1.0f + d, 0.0f);
                acc += (t4.w == t4.w) ? l : 0.0f;
            }
        }
        // diagonal (j==i) lies in this j-quarter iff prow==pj; its computed term is
        // exactly relu(1+0) = 1.0 (order=false since ti>ti is false) -> remove it.
        if (prow == pj) acc -= 1.0f;
    }

    // block reduction: wave64 shuffle, then cross-wave via LDS
    #pragma unroll
    for (int off = 32; off > 0; off >>= 1) acc += __shfl_down(acc, off);
    __shared__ float wsum[4];
    const int wid = tid >> 6, lane = tid & 63;
    if (lane == 0) wsum[wid] = acc;
    __syncthreads();
    if (tid == 0) {
        float s = wsum[0] + wsum[1] + wsum[2] + wsum[3];
        atomicAdd(&ws_loss[b], s);
    }
}

// ---------------- Kernel B: per-sample finalize ----------------
__global__ __launch_bounds__(256) void prl_sample(const float* __restrict__ T,
                                                  const float* __restrict__ ws_loss,
                                                  float* __restrict__ ws_acc) {
    const int b = blockIdx.x;
    const int tid = threadIdx.x;
    int cnt = 0;
    #pragma unroll
    for (int k = tid; k < BN; k += 256) {
        float t = T[b * BN + k];
        cnt += (t == t) ? 1 : 0;
    }
    #pragma unroll
    for (int off = 32; off > 0; off >>= 1) cnt += __shfl_down(cnt, off);
    __shared__ int wcnt[4];
    const int wid = tid >> 6, lane = tid & 63;
    if (lane == 0) wcnt[wid] = cnt;
    __syncthreads();
    if (tid == 0) {
        int nv = wcnt[0] + wcnt[1] + wcnt[2] + wcnt[3];
        float c = (float)nv * (float)(nv - 1);
        float sl = ws_loss[b] / fmaxf(c, 1.0f);
        if (nv > 1) {
            atomicAdd(&ws_acc[0], sl);    // sum of sample losses over ok samples
            atomicAdd(&ws_acc[1], 1.0f);  // num_ok
        }
    }
}

// ---------------- Kernel C: final scalar ----------------
__global__ void prl_final(const float* __restrict__ ws_acc, float* __restrict__ out) {
    float s = ws_acc[0], n = ws_acc[1];
    out[0] = (n > 0.0f) ? (s / n) : 0.0f;
}

extern "C" void kernel_launch(void* const* d_in, const int* in_sizes, int n_in,
                              void* d_out, int out_size, void* d_ws, size_t ws_size,
                              hipStream_t stream) {
    const float* P = (const float*)d_in[0];   // predictions [64,1024] f32
    const float* T = (const float*)d_in[1];   // targets     [64,1024] f32 (with NaNs)
    float* out = (float*)d_out;               // scalar f32

    float* ws_loss = (float*)d_ws;            // [64] per-sample pair-loss sums
    float* ws_acc  = ws_loss + NB;            // [2]  {sum_sample_loss, num_ok}

    // ws is re-poisoned 0xAA before every timed launch -> zero what we use
    hipMemsetAsync(d_ws, 0, (NB + 2) * sizeof(float), stream);

    prl_pairs <<<NB * 16, 256, 0, stream>>>(P, T, ws_loss);
    prl_sample<<<NB,      256, 0, stream>>>(T, ws_loss, ws_acc);
    prl_final <<<1,       1,   0, stream>>>(ws_acc, out);
}

// Round 2
// 64.194 us; speedup vs baseline: 1.2017x; 1.2017x over previous
//
#include <hip/hip_runtime.h>
#include <math.h>

// PairwiseRankingLoss: B=64, N=1024, margin=1.0
//   valid = ~isnan(targets); pairs (i,j), i!=j, both valid
//   loss_ij = relu(1 - (p_i - p_j)) if t_i > t_j else relu(1 + (p_i - p_j))
//   sample_loss = sum_ij / max(n_valid*(n_valid-1), 1)
//   out = mean over samples with n_valid > 1 (0 if none)
//
// Trick: stage invalid j as (t_j, p_j) := (-inf, -inf). For any VALID row i:
//   t_i > -inf  -> true branch -> relu(1 - p_i + (-inf)) = relu(-inf) = 0.
// So the per-pair validity test disappears; invalid ROWS are masked once at
// the end (their acc may contain NaN from inf-inf, select handles it).

#define BN 1024   // items per sample
#define NB 64     // samples
#define NPART 16  // j-partitions per sample
#define JP 64     // j's per partition

// ---------------- Kernel A: pairwise partial sums + valid counts ----------------
// grid = NB*NPART blocks; block = 256 threads; each thread owns 4 rows
// (i = tid + 256r), loops the block's 64 staged j's.
__global__ __launch_bounds__(256) void prl_pairs(const float* __restrict__ P,
                                                 const float* __restrict__ T,
                                                 float* __restrict__ ws_part,
                                                 int* __restrict__ ws_cnt) {
    const int blk = blockIdx.x;
    const int b   = blk >> 4;   // sample
    const int q   = blk & 15;   // j-partition
    const int tid = threadIdx.x;

    __shared__ __align__(16) float sp[JP];
    __shared__ __align__(16) float st[JP];

    if (tid < JP) {             // exactly one wave stages
        float t = T[b * BN + q * JP + tid];
        float p = P[b * BN + q * JP + tid];
        bool v = (t == t);
        st[tid] = v ? t : -INFINITY;
        sp[tid] = v ? p : -INFINITY;
        unsigned long long m = __ballot(v);
        if (tid == 0) ws_cnt[blk] = __popcll(m);
    }
    __syncthreads();

    float pi[4], ti[4], a1[4], b1[4], acc[4];
    #pragma unroll
    for (int r = 0; r < 4; ++r) {
        int i = tid + r * 256;
        pi[r]  = P[b * BN + i];
        ti[r]  = T[b * BN + i];
        a1[r]  = 1.0f - pi[r];  // relu(a1 + pj) when ti > tj
        b1[r]  = 1.0f + pi[r];  // relu(b1 - pj) otherwise
        acc[r] = 0.0f;
    }

    const float4* sp4 = (const float4*)sp;
    const float4* st4 = (const float4*)st;
    #pragma unroll
    for (int jj = 0; jj < JP / 4; ++jj) {
        const float4 p4 = sp4[jj];   // broadcast LDS reads (wave-uniform addr)
        const float4 t4 = st4[jj];
        #pragma unroll
        for (int r = 0; r < 4; ++r) {
            float e0 = (ti[r] > t4.x) ? (a1[r] + p4.x) : (b1[r] - p4.x);
            acc[r] += fmaxf(e0, 0.0f);
            float e1 = (ti[r] > t4.y) ? (a1[r] + p4.y) : (b1[r] - p4.y);
            acc[r] += fmaxf(e1, 0.0f);
            float e2 = (ti[r] > t4.z) ? (a1[r] + p4.z) : (b1[r] - p4.z);
            acc[r] += fmaxf(e2, 0.0f);
            float e3 = (ti[r] > t4.w) ? (a1[r] + p4.w) : (b1[r] - p4.w);
            acc[r] += fmaxf(e3, 0.0f);
        }
    }

    float total = 0.0f;
    #pragma unroll
    for (int r = 0; r < 4; ++r) {
        int i = tid + r * 256;
        // diagonal j==i lies in this partition iff (i>>6)==q; its term is
        // exactly relu(1+0)=1 (ti>ti false) -> remove it.
        float v = acc[r] - (((i >> 6) == q) ? 1.0f : 0.0f);
        bool vi = (ti[r] == ti[r]);
        total += vi ? v : 0.0f;   // invalid rows (possibly NaN acc) -> 0
    }

    // block reduction: wave shuffle then cross-wave LDS, single slot write
    #pragma unroll
    for (int off = 32; off > 0; off >>= 1) total += __shfl_down(total, off);
    __shared__ float wsum[4];
    const int wid = tid >> 6, lane = tid & 63;
    if (lane == 0) wsum[wid] = total;
    __syncthreads();
    if (tid == 0) ws_part[blk] = wsum[0] + wsum[1] + wsum[2] + wsum[3];
}

// ---------------- Kernel B: finalize (single wave) ----------------
__global__ __launch_bounds__(64) void prl_final(const float* __restrict__ ws_part,
                                                const int* __restrict__ ws_cnt,
                                                float* __restrict__ out) {
    const int s = threadIdx.x;   // sample 0..63
    float S = 0.0f;
    int   n = 0;
    #pragma unroll
    for (int k = 0; k < NPART; ++k) {
        S += ws_part[s * NPART + k];
        n += ws_cnt[s * NPART + k];
    }
    float c  = (float)n * (float)(n - 1);
    float sl = S / fmaxf(c, 1.0f);
    float ok = (n > 1) ? 1.0f : 0.0f;
    float num = sl * ok;
    #pragma unroll
    for (int off = 32; off > 0; off >>= 1) {
        num += __shfl_down(num, off);
        ok  += __shfl_down(ok, off);
    }
    if (s == 0) out[0] = (ok > 0.0f) ? (num / ok) : 0.0f;
}

extern "C" void kernel_launch(void* const* d_in, const int* in_sizes, int n_in,
                              void* d_out, int out_size, void* d_ws, size_t ws_size,
                              hipStream_t stream) {
    const float* P = (const float*)d_in[0];   // predictions [64,1024] f32
    const float* T = (const float*)d_in[1];   // targets     [64,1024] f32 (NaNs)
    float* out = (float*)d_out;               // scalar f32

    float* ws_part = (float*)d_ws;                  // [NB*NPART] partial sums
    int*   ws_cnt  = (int*)(ws_part + NB * NPART);  // [NB*NPART] valid counts
    // every slot is written unconditionally -> no zero-init, no memset

    prl_pairs<<<NB * NPART, 256, 0, stream>>>(P, T, ws_part, ws_cnt);
    prl_final<<<1, 64, 0, stream>>>(ws_part, ws_cnt, out);
}